// Round 2
// baseline (96.716 us; speedup 1.0000x reference)
//
#include <hip/hip_runtime.h>

// Problem constants (match reference)
#define HH 256
#define WW 512
#define NB 128
#define N_STUFF 11
#define N_SEG 19

// Native vector type so __builtin_nontemporal_* accepts it.
typedef float f4 __attribute__((ext_vector_type(4)));

constexpr int W4       = WW / 4;                  // 128 float4 groups per row
constexpr int PLANE_N4 = HH * W4;                 // 32768 groups per plane
constexpr int STUFF_N4 = N_STUFF * PLANE_N4;      // 360448 groups

// 256-thread blocks, 16 float4 groups per thread (stride 256) = 4096 groups/block.
// Fewer, fatter waves: amortize per-wave fixed costs (scalar loads, bound math,
// store drain) over 256 B/lane instead of 64 B/lane.
constexpr int GPT          = 16;                  // groups per thread
constexpr int GPB          = 256 * GPT;           // 4096 groups per block
constexpr int STUFF_BLOCKS = STUFF_N4 / GPB;      // 88 (exact)
constexpr int BLK_PER_BOX  = PLANE_N4 / GPB;      // 8 blocks per box (32 rows each)
constexpr int INST_BLOCKS  = NB * BLK_PER_BOX;    // 1024
constexpr int TOTAL_BLOCKS = STUFF_BLOCKS + INST_BLOCKS;  // 1112

__global__ __launch_bounds__(256)
void SegTerm_kernel(const int* __restrict__ cls,
                    const f4* __restrict__ seg4,
                    const float* __restrict__ boxes,
                    f4* __restrict__ out4)
{
    const int blk = blockIdx.x;
    const int t   = threadIdx.x;

    if (blk < STUFF_BLOCKS) {
        // Output 0: straight copy, read-once / write-once -> nontemporal both ways.
        const int base = blk * GPB + t;
        #pragma unroll
        for (int k = 0; k < GPT; ++k) {
            f4 v = __builtin_nontemporal_load(&seg4[base + k * 256]);
            __builtin_nontemporal_store(v, &out4[base + k * 256]);
        }
        return;
    }

    // Output 1: one block covers 32 rows of one box's plane.
    const int b2          = blk - STUFF_BLOCKS;
    const int box         = b2 >> 3;              // 8 blocks per box
    const int base_in_box = (b2 & 7) * GPB;       // group index within plane
    const int r0          = base_in_box >> 7;     // first row of this 32-row chunk
    f4* __restrict__ dst = out4 + STUFF_N4 + (size_t)box * PLANE_N4;

    const f4 zero = (f4){0.f, 0.f, 0.f, 0.f};
    const int c = cls[box];                       // block-uniform (scalar)

    // b = boxes[:,1:] * 0.25 (exact in fp32); jnp.round = RNE -> rintf
    int x0 = 0, y0 = 0, x1 = 0, y1 = 0;
    bool allzero = (c == 0);
    if (!allzero) {
        const float bx0 = boxes[box * 5 + 1] * 0.25f;
        const float by0 = boxes[box * 5 + 2] * 0.25f;
        const float bx1 = boxes[box * 5 + 3] * 0.25f;
        const float by1 = boxes[box * 5 + 4] * 0.25f;
        x0 = (int)floorf(bx0);
        y0 = (int)floorf(by0);
        x1 = (int)(rintf(bx1) + 1.0f);
        y1 = (int)(rintf(by1) + 1.0f);
        // Whole 32-row chunk outside the box (or degenerate x-range)?
        allzero = (y1 <= r0) | (y0 >= r0 + 32) | (x1 <= x0) | (x1 <= 0) | (x0 >= WW);
    }

    if (allzero) {
        // ~70% of inst blocks: branchless streaming zero-fill.
        #pragma unroll
        for (int k = 0; k < GPT; ++k)
            __builtin_nontemporal_store(zero, &dst[base_in_box + k * 256 + t]);
        return;
    }

    const int mapped = min(c + 10, N_SEG - 1);
    const f4* __restrict__ src = seg4 + (size_t)mapped * PLANE_N4;

    #pragma unroll
    for (int k = 0; k < GPT; ++k) {
        const int gi = base_in_box + k * 256 + t;
        const int y  = gi >> 7;                   // row within plane
        const int xg = gi & (W4 - 1);
        const int x  = xg << 2;

        f4 v = zero;
        if (y >= y0 && y < y1) {
            if (x >= x0 && x + 3 < x1) {
                v = src[(y << 7) + xg];           // fully-interior: aligned 16B (L2-resident)
            } else if (x + 3 >= x0 && x < x1) {
                const float* s = (const float*)(src + (y << 7)) + x;
                v.x = (x     >= x0 && x     < x1) ? s[0] : 0.f;
                v.y = (x + 1 >= x0 && x + 1 < x1) ? s[1] : 0.f;
                v.z = (x + 2 >= x0 && x + 2 < x1) ? s[2] : 0.f;
                v.w = (x + 3 >= x0 && x + 3 < x1) ? s[3] : 0.f;
            }
        }
        __builtin_nontemporal_store(v, &dst[gi]);
    }
}

extern "C" void kernel_launch(void* const* d_in, const int* in_sizes, int n_in,
                              void* d_out, int out_size, void* d_ws, size_t ws_size,
                              hipStream_t stream) {
    const int*  cls   = (const int*)d_in[0];
    const f4*   seg4  = (const f4*)d_in[1];
    const float* boxes = (const float*)d_in[2];
    f4*         out4  = (f4*)d_out;

    SegTerm_kernel<<<TOTAL_BLOCKS, 256, 0, stream>>>(cls, seg4, boxes, out4);
}